// Round 15
// baseline (1042.866 us; speedup 1.0000x reference)
//
#include <hip/hip_runtime.h>

#define DIM 64
#define SCAN_T 256
#define SCAN_E 8
#define SCAN_CHUNK (SCAN_T * SCAN_E)   // 2048 rows per scan block (fallback)
#define BSHIFT 9                       // 512 rows per bucket
#define BROWS (1 << BSHIFT)
#define PBLK 512                       // partition blocks
#define MAXBUK 512                     // max buckets (N <= 2^18 at BSHIFT=9)

typedef unsigned int u32;
typedef unsigned long long u64;
typedef unsigned short u16;

// ---- packed (col,val): col in bits [31:14] (col < 2^18), val as 14-bit fixed ----
__device__ __forceinline__ u32 packCV(int col, float v) {
    int q = (int)(v * 16384.f + 0.5f);
    q = min(q, 16383);
    return ((u32)col << 14) | (u32)q;
}

__device__ __forceinline__ u16 f2bf(float f) {
    u32 u = __float_as_uint(f);
    u32 r = u + 0x7FFFu + ((u >> 16) & 1u);   // RNE
    return (u16)(r >> 16);
}
__device__ __forceinline__ float bf2f(u16 h) {
    return __uint_as_float((u32)h << 16);
}

// ---------------------------------------------------------------------------
// ego f32 -> bf16 table
// ---------------------------------------------------------------------------
__global__ void cvt_k(const float* __restrict__ src, u16* __restrict__ dst, int n4) {
    int i = blockIdx.x * blockDim.x + threadIdx.x;
    if (i < n4) {
        float4 f = reinterpret_cast<const float4*>(src)[i];
        ushort4 h;
        h.x = f2bf(f.x); h.y = f2bf(f.y); h.z = f2bf(f.z); h.w = f2bf(f.w);
        reinterpret_cast<ushort4*>(dst)[i] = h;
    }
}

// ---------------------------------------------------------------------------
// Atomic-free-in-global CSR build (R10/R11, measured ~99us total) — UNCHANGED.
// R7 lesson: never funnel per-edge atomics onto few GLOBAL addresses.
// ---------------------------------------------------------------------------

// 1) per-(bucket,block) histogram, LDS only
__global__ __launch_bounds__(256) void histb_k(const int* __restrict__ erow,
                                               int* __restrict__ bhist,   // [MAXBUK][PBLK]
                                               int E, int CH, int nbuk) {
    __shared__ int h[MAXBUK];
    const int tid = threadIdx.x;
    for (int i = tid; i < nbuk; i += 256) h[i] = 0;
    __syncthreads();
    const int s = blockIdx.x * CH;
    const int e = min(E, s + CH);
    for (int i4 = s + tid * 4; i4 < e; i4 += 256 * 4) {
        if (i4 + 3 < e) {
            const int4 r = *reinterpret_cast<const int4*>(erow + i4);
            atomicAdd(&h[r.x >> BSHIFT], 1);
            atomicAdd(&h[r.y >> BSHIFT], 1);
            atomicAdd(&h[r.z >> BSHIFT], 1);
            atomicAdd(&h[r.w >> BSHIFT], 1);
        } else {
            for (int i = i4; i < e; ++i) atomicAdd(&h[erow[i] >> BSHIFT], 1);
        }
    }
    __syncthreads();
    for (int i = tid; i < nbuk; i += 256) bhist[i * PBLK + blockIdx.x] = h[i];
}

// 2) per-bucket: exclusive prefix over blocks, in place; bucket total out
__global__ void bbase_k(int* __restrict__ bhist, int* __restrict__ bktTot) {
    __shared__ int sh[SCAN_T];
    const int bk  = blockIdx.x;
    const int tid = threadIdx.x;
    const int v0 = bhist[bk * PBLK + 2 * tid];
    const int v1 = bhist[bk * PBLK + 2 * tid + 1];
    sh[tid] = v0 + v1;
    __syncthreads();
    for (int off = 1; off < SCAN_T; off <<= 1) {
        int t = (tid >= off) ? sh[tid - off] : 0;
        __syncthreads();
        sh[tid] += t;
        __syncthreads();
    }
    const int excl = (tid == 0) ? 0 : sh[tid - 1];
    bhist[bk * PBLK + 2 * tid]     = excl;
    bhist[bk * PBLK + 2 * tid + 1] = excl + v0;
    if (tid == SCAN_T - 1) bktTot[bk] = sh[SCAN_T - 1];
}

// 3) bucket bases: tiny LDS scan over <=MAXBUK totals
__global__ void scanBk_k(const int* __restrict__ tot, int* __restrict__ base, int nbuk) {
    __shared__ int sh[MAXBUK + 1];
    const int tid = threadIdx.x;   // 512
    for (int i = tid; i < nbuk; i += 512) sh[i] = tot[i];
    __syncthreads();
    if (tid == 0) {
        int s = 0;
        for (int i = 0; i < nbuk; ++i) { int t = sh[i]; sh[i] = s; s += t; }
        sh[nbuk] = s;
    }
    __syncthreads();
    for (int i = tid; i <= nbuk; i += 512) base[i] = sh[i];
}

// 4) scatter edges into bucket-major tmp; LDS cursors; contiguous runs
__global__ __launch_bounds__(256) void part_k(const int* __restrict__ erow,
                                              const int* __restrict__ ecol,
                                              const float* __restrict__ ev,
                                              const int* __restrict__ bhist,
                                              const int* __restrict__ bktBase,
                                              u32* __restrict__ tcv,
                                              u16* __restrict__ trow,
                                              int E, int CH, int nbuk) {
    __shared__ int cur[MAXBUK];
    const int tid = threadIdx.x;
    for (int i = tid; i < nbuk; i += 256)
        cur[i] = bktBase[i] + bhist[i * PBLK + blockIdx.x];
    __syncthreads();
    const int s = blockIdx.x * CH;
    const int e = min(E, s + CH);
    const int lm = BROWS - 1;
    for (int i4 = s + tid * 4; i4 < e; i4 += 256 * 4) {
        if (i4 + 3 < e) {
            const int4   r = *reinterpret_cast<const int4*>(erow + i4);
            const int4   c = *reinterpret_cast<const int4*>(ecol + i4);
            const float4 v = *reinterpret_cast<const float4*>(ev + i4);
            int p;
            p = atomicAdd(&cur[r.x >> BSHIFT], 1); tcv[p] = packCV(c.x, v.x); trow[p] = (u16)(r.x & lm);
            p = atomicAdd(&cur[r.y >> BSHIFT], 1); tcv[p] = packCV(c.y, v.y); trow[p] = (u16)(r.y & lm);
            p = atomicAdd(&cur[r.z >> BSHIFT], 1); tcv[p] = packCV(c.z, v.z); trow[p] = (u16)(r.z & lm);
            p = atomicAdd(&cur[r.w >> BSHIFT], 1); tcv[p] = packCV(c.w, v.w); trow[p] = (u16)(r.w & lm);
        } else {
            for (int i = i4; i < e; ++i) {
                const int r = erow[i];
                const int p = atomicAdd(&cur[r >> BSHIFT], 1);
                tcv[p] = packCV(ecol[i], ev[i]);
                trow[p] = (u16)(r & lm);
            }
        }
    }
}

// 5) per bucket: LDS per-row count -> LDS scan -> write offs + row-scatter scv
__global__ __launch_bounds__(512) void final2_k(const u32* __restrict__ tcv,
                                                const u16* __restrict__ trow,
                                                const int* __restrict__ bktBase,
                                                int* __restrict__ offs,
                                                u32* __restrict__ scv,
                                                int N, int nbuk) {
    __shared__ int rcur[BROWS];
    __shared__ int sc[BROWS];
    const int tid  = threadIdx.x;   // 512 == BROWS
    const int bk   = blockIdx.x;
    const int row0 = bk << BSHIFT;
    const int rows = min(BROWS, N - row0);
    const int s = bktBase[bk];
    const int e = bktBase[bk + 1];
    rcur[tid] = 0;
    __syncthreads();
    for (int i = s + tid; i < e; i += 512) atomicAdd(&rcur[trow[i]], 1);
    __syncthreads();
    sc[tid] = rcur[tid];
    __syncthreads();
    for (int off = 1; off < BROWS; off <<= 1) {
        int t = (tid >= off) ? sc[tid - off] : 0;
        __syncthreads();
        sc[tid] += t;
        __syncthreads();
    }
    const int excl = (tid == 0) ? 0 : sc[tid - 1];
    rcur[tid] = s + excl;
    if (tid < rows) offs[row0 + tid] = s + excl;
    if (bk == nbuk - 1 && tid == 0) offs[N] = e;
    __syncthreads();
    for (int i = s + tid; i < e; i += 512) {
        const u32 cv = tcv[i];
        const int lr = trow[i];
        const int p = atomicAdd(&rcur[lr], 1);
        scv[p] = cv;
    }
}

// ---------------------------------------------------------------------------
// Fallback tier kernels (per-row global cursors / atomic scatter)
// ---------------------------------------------------------------------------
__global__ void hist_k(const int* __restrict__ erow, int* __restrict__ cnt, int E) {
    const int e4 = (blockIdx.x * blockDim.x + threadIdx.x) * 4;
    if (e4 + 3 < E) {
        const int4 r = *reinterpret_cast<const int4*>(erow + e4);
        atomicAdd(&cnt[r.x], 1);
        atomicAdd(&cnt[r.y], 1);
        atomicAdd(&cnt[r.z], 1);
        atomicAdd(&cnt[r.w], 1);
    } else {
        for (int e = e4; e < E; ++e) atomicAdd(&cnt[erow[e]], 1);
    }
}

__global__ void scanA_k(const int* __restrict__ cnt, int* __restrict__ offs,
                        int* __restrict__ bsums, int N) {
    __shared__ int sh[SCAN_T];
    const int base = blockIdx.x * SCAN_CHUNK + threadIdx.x * SCAN_E;
    int v[SCAN_E];
    int s = 0;
#pragma unroll
    for (int j = 0; j < SCAN_E; ++j) {
        int idx = base + j;
        int c = (idx < N) ? cnt[idx] : 0;
        v[j] = s;
        s += c;
    }
    sh[threadIdx.x] = s;
    __syncthreads();
    for (int off = 1; off < SCAN_T; off <<= 1) {
        int t = (threadIdx.x >= off) ? sh[threadIdx.x - off] : 0;
        __syncthreads();
        sh[threadIdx.x] += t;
        __syncthreads();
    }
    const int excl = (threadIdx.x == 0) ? 0 : sh[threadIdx.x - 1];
    if (threadIdx.x == SCAN_T - 1) bsums[blockIdx.x] = sh[SCAN_T - 1];
#pragma unroll
    for (int j = 0; j < SCAN_E; ++j) {
        int idx = base + j;
        if (idx < N) offs[idx] = v[j] + excl;
    }
}

__global__ void scanB_k(int* __restrict__ bsums, int nb) {
    __shared__ int sh[1024];
    const int tid = threadIdx.x;
    if (tid < nb) sh[tid] = bsums[tid];
    __syncthreads();
    if (tid == 0) {
        int s = 0;
        for (int i = 0; i < nb; ++i) { int t = sh[i]; sh[i] = s; s += t; }
    }
    __syncthreads();
    if (tid < nb) bsums[tid] = sh[tid];
}

__global__ void scanC_k(int* __restrict__ offs, int* __restrict__ cursor,
                        const int* __restrict__ bsums, int N, int E) {
    const int i = blockIdx.x * blockDim.x + threadIdx.x;
    if (i < N) {
        int v = offs[i] + bsums[i / SCAN_CHUNK];
        offs[i] = v;
        cursor[i] = v;
    }
    if (i == 0) offs[N] = E;
}

__global__ void reorder_k(const int* __restrict__ erow, const int* __restrict__ ecol,
                          const float* __restrict__ ev, int* __restrict__ cursor,
                          u32* __restrict__ scv, int E) {
    const int e4 = (blockIdx.x * blockDim.x + threadIdx.x) * 4;
    if (e4 + 3 < E) {
        const int4   r = *reinterpret_cast<const int4*>(erow + e4);
        const int4   c = *reinterpret_cast<const int4*>(ecol + e4);
        const float4 v = *reinterpret_cast<const float4*>(ev + e4);
        int p;
        p = atomicAdd(&cursor[r.x], 1); scv[p] = packCV(c.x, v.x);
        p = atomicAdd(&cursor[r.y], 1); scv[p] = packCV(c.y, v.y);
        p = atomicAdd(&cursor[r.z], 1); scv[p] = packCV(c.z, v.z);
        p = atomicAdd(&cursor[r.w], 1); scv[p] = packCV(c.w, v.w);
    } else {
        for (int e = e4; e < E; ++e) {
            int p = atomicAdd(&cursor[erow[e]], 1);
            scv[p] = packCV(ecol[e], ev[e]);
        }
    }
}

// ---------------------------------------------------------------------------
// Fused segment-sum + bi-interaction MLP — EXACT R9/R11 body (measured 214us,
// VALUBusy 58%, best of 5 structural variants). SINGLE CHANGE this round:
// __launch_bounds__(256, 8) caps the allocator at 64 VGPRs (the 8-waves/SIMD
// occupancy threshold, m69). R13 proved weight reloads are free, so shedding
// register pressure should cost nothing; if occupancy was VGPR-bound this
// raises resident waves 6->8 per SIMD for a latency-bound kernel.
// ---------------------------------------------------------------------------
__device__ __forceinline__ float lrelu(float x) {
    return fmaxf(x, 0.f) + 0.01f * fminf(x, 0.f);
}

template <bool BF16>
__global__ __launch_bounds__(256, 8) void fused_k(const float* __restrict__ ego,
                                                  const u16* __restrict__ egoh,
                                                  const float* __restrict__ W1,
                                                  const float* __restrict__ b1,
                                                  const float* __restrict__ W2,
                                                  const float* __restrict__ b2,
                                                  const int* __restrict__ offs,
                                                  const u32* __restrict__ scv,
                                                  float* __restrict__ out,
                                                  int N, int rowsPerWave) {
    __shared__ __align__(16) float xsh[4][2][DIM];
    const int lane = threadIdx.x & 63;
    const int wid  = threadIdx.x >> 6;

    float w1[DIM], w2[DIM];
#pragma unroll
    for (int k = 0; k < DIM; ++k) {
        w1[k] = W1[k * DIM + lane];
        w2[k] = W2[k * DIM + lane];
    }
    const float bb1 = b1[lane];
    const float bb2 = b2[lane];

    const int waveId = blockIdx.x * 4 + wid;
    const int r0 = waveId * rowsPerWave;
    const int r1 = min(N, r0 + rowsPerWave);

    for (int row = r0; row < r1; ++row) {
        const int s = offs[row];
        const int t = offs[row + 1];
        float acc = 0.f;
        for (int base = s; base < t; base += 64) {
            const int m = min(64, t - base);
            const u32 cv = (lane < m) ? scv[base + lane] : 0u;
            for (int j = 0; j < m; j += 8) {
                u32 uu[8];
#pragma unroll
                for (int i = 0; i < 8; ++i) {
                    const int sj = j + i;
                    const u32 x = (u32)__shfl((int)cv, sj & 63);
                    uu[i] = (sj < m) ? x : 0u;
                }
                float g[8];
#pragma unroll
                for (int i = 0; i < 8; ++i) {
                    if (BF16) g[i] = bf2f(egoh[(uu[i] >> 14) * DIM + lane]);
                    else      g[i] = ego[(uu[i] >> 14) * DIM + lane];
                }
                const float sc = 1.f / 16384.f;
#pragma unroll
                for (int i = 0; i < 8; ++i)
                    acc = fmaf((float)(uu[i] & 16383u) * sc, g[i], acc);
            }
        }
        // ---- fused bi-interaction MLP (x broadcast via LDS) ----
        const int obase = row * DIM + lane;
        const float e = ego[obase];
        xsh[wid][0][lane] = e + acc;
        xsh[wid][1][lane] = e * acc;
        float a1 = bb1, a2 = bb2;
#pragma unroll
        for (int k4 = 0; k4 < 16; ++k4) {
            const float4 xa = *reinterpret_cast<const float4*>(&xsh[wid][0][k4 * 4]);
            const float4 xm = *reinterpret_cast<const float4*>(&xsh[wid][1][k4 * 4]);
            a1 = fmaf(xa.x, w1[4 * k4 + 0], a1);
            a1 = fmaf(xa.y, w1[4 * k4 + 1], a1);
            a1 = fmaf(xa.z, w1[4 * k4 + 2], a1);
            a1 = fmaf(xa.w, w1[4 * k4 + 3], a1);
            a2 = fmaf(xm.x, w2[4 * k4 + 0], a2);
            a2 = fmaf(xm.y, w2[4 * k4 + 1], a2);
            a2 = fmaf(xm.z, w2[4 * k4 + 2], a2);
            a2 = fmaf(xm.w, w2[4 * k4 + 3], a2);
        }
        out[obase] = lrelu(a1) + lrelu(a2);
    }
}

// ---------------------------------------------------------------------------
// Atomic fallback path
// ---------------------------------------------------------------------------
__device__ __forceinline__ void atomAddF(float* p, float v) {
    __hip_atomic_fetch_add(p, v, __ATOMIC_RELAXED, __HIP_MEMORY_SCOPE_AGENT);
}

__global__ void scatter_k(const float* __restrict__ ego,
                          const int* __restrict__ erow,
                          const int* __restrict__ ecol,
                          const float* __restrict__ eval_,
                          float* __restrict__ side,
                          long long total16) {
    long long tid = (long long)blockIdx.x * blockDim.x + threadIdx.x;
    if (tid >= total16) return;
    const int e = (int)(tid >> 4);
    const int q = (int)(tid & 15);
    const float4 g = *reinterpret_cast<const float4*>(ego + (size_t)ecol[e] * DIM + q * 4);
    const float v = eval_[e];
    float* dst = side + (size_t)erow[e] * DIM + q * 4;
    atomAddF(dst + 0, g.x * v);
    atomAddF(dst + 1, g.y * v);
    atomAddF(dst + 2, g.z * v);
    atomAddF(dst + 3, g.w * v);
}

__global__ __launch_bounds__(256) void mlp_k(const float* __restrict__ ego,
                                             const float* __restrict__ W1,
                                             const float* __restrict__ b1,
                                             const float* __restrict__ W2,
                                             const float* __restrict__ b2,
                                             float* out, int nNodes) {
    __shared__ __align__(16) float xsh[4][2][DIM];
    const int lane = threadIdx.x & 63;
    const int wid  = threadIdx.x >> 6;
    float w1[DIM], w2[DIM];
#pragma unroll
    for (int k = 0; k < DIM; ++k) {
        w1[k] = W1[k * DIM + lane];
        w2[k] = W2[k * DIM + lane];
    }
    const float bb1 = b1[lane];
    const float bb2 = b2[lane];
    const int waveId = blockIdx.x * 4 + wid;
    const int nWaves = gridDim.x * 4;
    for (int n = waveId; n < nNodes; n += nWaves) {
        const size_t base = (size_t)n * DIM + lane;
        const float e = ego[base];
        const float s = out[base];
        xsh[wid][0][lane] = e + s;
        xsh[wid][1][lane] = e * s;
        float acc1 = bb1, acc2 = bb2;
#pragma unroll
        for (int k4 = 0; k4 < 16; ++k4) {
            const float4 a = *reinterpret_cast<const float4*>(&xsh[wid][0][k4 * 4]);
            const float4 m = *reinterpret_cast<const float4*>(&xsh[wid][1][k4 * 4]);
            acc1 = fmaf(a.x, w1[4 * k4 + 0], acc1);
            acc1 = fmaf(a.y, w1[4 * k4 + 1], acc1);
            acc1 = fmaf(a.z, w1[4 * k4 + 2], acc1);
            acc1 = fmaf(a.w, w1[4 * k4 + 3], acc1);
            acc2 = fmaf(m.x, w2[4 * k4 + 0], acc2);
            acc2 = fmaf(m.y, w2[4 * k4 + 1], acc2);
            acc2 = fmaf(m.z, w2[4 * k4 + 2], acc2);
            acc2 = fmaf(m.w, w2[4 * k4 + 3], acc2);
        }
        const float r1 = fmaxf(acc1, 0.f) + 0.01f * fminf(acc1, 0.f);
        const float r2 = fmaxf(acc2, 0.f) + 0.01f * fminf(acc2, 0.f);
        out[base] = r1 + r2;
    }
}

// ---------------------------------------------------------------------------
extern "C" void kernel_launch(void* const* d_in, const int* in_sizes, int n_in,
                              void* d_out, int out_size, void* d_ws, size_t ws_size,
                              hipStream_t stream) {
    const float* ego  = (const float*)d_in[0];
    const float* W1   = (const float*)d_in[1];
    const float* b1   = (const float*)d_in[2];
    const float* W2   = (const float*)d_in[3];
    const float* b2   = (const float*)d_in[4];
    const int*   erow = (const int*)d_in[5];
    const int*   ecol = (const int*)d_in[6];
    const float* ev   = (const float*)d_in[7];
    float* out = (float*)d_out;

    const int N = in_sizes[0] / DIM;
    const int E = in_sizes[5];

    auto align256 = [](size_t x) { return (x + 63) & ~(size_t)63; };  // int units
    const int nbuk = (N + BROWS - 1) >> BSHIFT;

    size_t o_cnt     = 0;                                    // N (fallback)
    size_t o_offs    = align256(o_cnt + N);                  // N+1
    size_t o_cursor  = align256(o_offs + N + 1);             // N (fallback)
    size_t o_bsums   = align256(o_cursor + N);               // 1024 (fallback)
    size_t o_scv     = align256(o_bsums + 1024);             // E
    size_t o_egoh    = align256(o_scv + E);                  // N*DIM u16 = N*32 ints
    size_t o_bhist   = align256(o_egoh + (size_t)N * (DIM / 2));
    size_t o_bktTot  = align256(o_bhist + (size_t)MAXBUK * PBLK);
    size_t o_bktBase = align256(o_bktTot + MAXBUK);
    size_t o_tcv     = align256(o_bktBase + MAXBUK + 1);
    size_t o_trow    = align256(o_tcv + E);
    size_t need_main = (o_trow + (size_t)(E + 1) / 2) * sizeof(int);
    size_t need_fb1  = (o_bhist) * sizeof(int);              // through egoh
    size_t need_fb2  = (o_egoh) * sizeof(int);               // through scv

    const bool packOK = (N <= (1 << 18));

    if (!packOK || ws_size < need_fb2) {
        hipMemsetAsync(out, 0, (size_t)out_size * sizeof(float), stream);
        const long long total16 = (long long)E * 16;
        scatter_k<<<(int)((total16 + 255) / 256), 256, 0, stream>>>(ego, erow, ecol, ev, out, total16);
        mlp_k<<<1024, 256, 0, stream>>>(ego, W1, b1, W2, b2, out, N);
        return;
    }

    int* ws = (int*)d_ws;
    int* cnt     = ws + o_cnt;
    int* offs    = ws + o_offs;
    int* cursor  = ws + o_cursor;
    int* bsums   = ws + o_bsums;
    u32* scv     = (u32*)(ws + o_scv);
    u16* egoh    = (u16*)(ws + o_egoh);
    int* bhist   = ws + o_bhist;
    int* bktTot  = ws + o_bktTot;
    int* bktBase = ws + o_bktBase;
    u32* tcv     = (u32*)(ws + o_tcv);
    u16* trow    = (u16*)(ws + o_trow);

    const bool useBF16  = ws_size >= need_fb1;
    const bool useRadix = (ws_size >= need_main) && (nbuk <= MAXBUK) && useBF16;

    if (useRadix) {
        const int CH = (((E + PBLK - 1) / PBLK) + 3) & ~3;
        histb_k<<<PBLK, 256, 0, stream>>>(erow, bhist, E, CH, nbuk);
        bbase_k<<<nbuk, SCAN_T, 0, stream>>>(bhist, bktTot);
        scanBk_k<<<1, 512, 0, stream>>>(bktTot, bktBase, nbuk);
        part_k<<<PBLK, 256, 0, stream>>>(erow, ecol, ev, bhist, bktBase, tcv, trow, E, CH, nbuk);
        final2_k<<<nbuk, 512, 0, stream>>>(tcv, trow, bktBase, offs, scv, N, nbuk);
        const int n4 = N * DIM / 4;
        cvt_k<<<(n4 + 255) / 256, 256, 0, stream>>>(ego, egoh, n4);
    } else {
        const int nb = (N + SCAN_CHUNK - 1) / SCAN_CHUNK;
        hipMemsetAsync(cnt, 0, (size_t)N * sizeof(int), stream);
        hist_k<<<(E / 4 + 255) / 256, 256, 0, stream>>>(erow, cnt, E);
        if (useBF16) {
            const int n4 = N * DIM / 4;
            cvt_k<<<(n4 + 255) / 256, 256, 0, stream>>>(ego, egoh, n4);
        }
        scanA_k<<<nb, SCAN_T, 0, stream>>>(cnt, offs, bsums, N);
        scanB_k<<<1, 1024, 0, stream>>>(bsums, nb);
        scanC_k<<<(N + 255) / 256, 256, 0, stream>>>(offs, cursor, bsums, N, E);
        reorder_k<<<(E / 4 + 255) / 256, 256, 0, stream>>>(erow, ecol, ev, cursor, scv, E);
    }

    const int nBlocks = 2048;
    const int nWaves = nBlocks * 4;
    const int rowsPerWave = (N + nWaves - 1) / nWaves;
    if (useBF16) {
        fused_k<true><<<nBlocks, 256, 0, stream>>>(ego, egoh, W1, b1, W2, b2, offs, scv, out, N, rowsPerWave);
    } else {
        fused_k<false><<<nBlocks, 256, 0, stream>>>(ego, egoh, W1, b1, W2, b2, offs, scv, out, N, rowsPerWave);
    }
}

// Round 16
// 314.092 us; speedup vs baseline: 3.3203x; 3.3203x over previous
//
#include <hip/hip_runtime.h>

#define DIM 64
#define SCAN_T 256
#define SCAN_E 8
#define SCAN_CHUNK (SCAN_T * SCAN_E)   // 2048 rows per scan block (fallback)
#define BSHIFT 9                       // 512 rows per bucket
#define BROWS (1 << BSHIFT)
#define PBLK 512                       // partition blocks
#define MAXBUK 512                     // max buckets (N <= 2^18 at BSHIFT=9)

typedef unsigned int u32;
typedef unsigned long long u64;
typedef unsigned short u16;

// ---- packed (col,val): col in bits [31:14] (col < 2^18), val as 14-bit fixed ----
__device__ __forceinline__ u32 packCV(int col, float v) {
    int q = (int)(v * 16384.f + 0.5f);
    q = min(q, 16383);
    return ((u32)col << 14) | (u32)q;
}

__device__ __forceinline__ u16 f2bf(float f) {
    u32 u = __float_as_uint(f);
    u32 r = u + 0x7FFFu + ((u >> 16) & 1u);   // RNE
    return (u16)(r >> 16);
}
__device__ __forceinline__ float bf2f(u16 h) {
    return __uint_as_float((u32)h << 16);
}

// ---------------------------------------------------------------------------
// ego f32 -> bf16 table
// ---------------------------------------------------------------------------
__global__ void cvt_k(const float* __restrict__ src, u16* __restrict__ dst, int n4) {
    int i = blockIdx.x * blockDim.x + threadIdx.x;
    if (i < n4) {
        float4 f = reinterpret_cast<const float4*>(src)[i];
        ushort4 h;
        h.x = f2bf(f.x); h.y = f2bf(f.y); h.z = f2bf(f.z); h.w = f2bf(f.w);
        reinterpret_cast<ushort4*>(dst)[i] = h;
    }
}

// ---------------------------------------------------------------------------
// Atomic-free-in-global CSR build (R10/R11, measured ~99us total).
// R7 lesson: never funnel per-edge atomics onto few GLOBAL addresses.
// ---------------------------------------------------------------------------

// 1) per-(bucket,block) histogram, LDS only
__global__ __launch_bounds__(256) void histb_k(const int* __restrict__ erow,
                                               int* __restrict__ bhist,   // [MAXBUK][PBLK]
                                               int E, int CH, int nbuk) {
    __shared__ int h[MAXBUK];
    const int tid = threadIdx.x;
    for (int i = tid; i < nbuk; i += 256) h[i] = 0;
    __syncthreads();
    const int s = blockIdx.x * CH;
    const int e = min(E, s + CH);
    for (int i4 = s + tid * 4; i4 < e; i4 += 256 * 4) {
        if (i4 + 3 < e) {
            const int4 r = *reinterpret_cast<const int4*>(erow + i4);
            atomicAdd(&h[r.x >> BSHIFT], 1);
            atomicAdd(&h[r.y >> BSHIFT], 1);
            atomicAdd(&h[r.z >> BSHIFT], 1);
            atomicAdd(&h[r.w >> BSHIFT], 1);
        } else {
            for (int i = i4; i < e; ++i) atomicAdd(&h[erow[i] >> BSHIFT], 1);
        }
    }
    __syncthreads();
    for (int i = tid; i < nbuk; i += 256) bhist[i * PBLK + blockIdx.x] = h[i];
}

// 2) per-bucket: exclusive prefix over blocks, in place; bucket total out
__global__ void bbase_k(int* __restrict__ bhist, int* __restrict__ bktTot) {
    __shared__ int sh[SCAN_T];
    const int bk  = blockIdx.x;
    const int tid = threadIdx.x;
    const int v0 = bhist[bk * PBLK + 2 * tid];
    const int v1 = bhist[bk * PBLK + 2 * tid + 1];
    sh[tid] = v0 + v1;
    __syncthreads();
    for (int off = 1; off < SCAN_T; off <<= 1) {
        int t = (tid >= off) ? sh[tid - off] : 0;
        __syncthreads();
        sh[tid] += t;
        __syncthreads();
    }
    const int excl = (tid == 0) ? 0 : sh[tid - 1];
    bhist[bk * PBLK + 2 * tid]     = excl;
    bhist[bk * PBLK + 2 * tid + 1] = excl + v0;
    if (tid == SCAN_T - 1) bktTot[bk] = sh[SCAN_T - 1];
}

// 3) bucket bases: tiny LDS scan over <=MAXBUK totals
__global__ void scanBk_k(const int* __restrict__ tot, int* __restrict__ base, int nbuk) {
    __shared__ int sh[MAXBUK + 1];
    const int tid = threadIdx.x;   // 512
    for (int i = tid; i < nbuk; i += 512) sh[i] = tot[i];
    __syncthreads();
    if (tid == 0) {
        int s = 0;
        for (int i = 0; i < nbuk; ++i) { int t = sh[i]; sh[i] = s; s += t; }
        sh[nbuk] = s;
    }
    __syncthreads();
    for (int i = tid; i <= nbuk; i += 512) base[i] = sh[i];
}

// 4) scatter edges into bucket-major tmp; LDS cursors; contiguous runs
__global__ __launch_bounds__(256) void part_k(const int* __restrict__ erow,
                                              const int* __restrict__ ecol,
                                              const float* __restrict__ ev,
                                              const int* __restrict__ bhist,
                                              const int* __restrict__ bktBase,
                                              u32* __restrict__ tcv,
                                              u16* __restrict__ trow,
                                              int E, int CH, int nbuk) {
    __shared__ int cur[MAXBUK];
    const int tid = threadIdx.x;
    for (int i = tid; i < nbuk; i += 256)
        cur[i] = bktBase[i] + bhist[i * PBLK + blockIdx.x];
    __syncthreads();
    const int s = blockIdx.x * CH;
    const int e = min(E, s + CH);
    const int lm = BROWS - 1;
    for (int i4 = s + tid * 4; i4 < e; i4 += 256 * 4) {
        if (i4 + 3 < e) {
            const int4   r = *reinterpret_cast<const int4*>(erow + i4);
            const int4   c = *reinterpret_cast<const int4*>(ecol + i4);
            const float4 v = *reinterpret_cast<const float4*>(ev + i4);
            int p;
            p = atomicAdd(&cur[r.x >> BSHIFT], 1); tcv[p] = packCV(c.x, v.x); trow[p] = (u16)(r.x & lm);
            p = atomicAdd(&cur[r.y >> BSHIFT], 1); tcv[p] = packCV(c.y, v.y); trow[p] = (u16)(r.y & lm);
            p = atomicAdd(&cur[r.z >> BSHIFT], 1); tcv[p] = packCV(c.z, v.z); trow[p] = (u16)(r.z & lm);
            p = atomicAdd(&cur[r.w >> BSHIFT], 1); tcv[p] = packCV(c.w, v.w); trow[p] = (u16)(r.w & lm);
        } else {
            for (int i = i4; i < e; ++i) {
                const int r = erow[i];
                const int p = atomicAdd(&cur[r >> BSHIFT], 1);
                tcv[p] = packCV(ecol[i], ev[i]);
                trow[p] = (u16)(r & lm);
            }
        }
    }
}

// 5) per bucket: LDS per-row count -> LDS scan -> write offs + row-scatter scv
__global__ __launch_bounds__(512) void final2_k(const u32* __restrict__ tcv,
                                                const u16* __restrict__ trow,
                                                const int* __restrict__ bktBase,
                                                int* __restrict__ offs,
                                                u32* __restrict__ scv,
                                                int N, int nbuk) {
    __shared__ int rcur[BROWS];
    __shared__ int sc[BROWS];
    const int tid  = threadIdx.x;   // 512 == BROWS
    const int bk   = blockIdx.x;
    const int row0 = bk << BSHIFT;
    const int rows = min(BROWS, N - row0);
    const int s = bktBase[bk];
    const int e = bktBase[bk + 1];
    rcur[tid] = 0;
    __syncthreads();
    for (int i = s + tid; i < e; i += 512) atomicAdd(&rcur[trow[i]], 1);
    __syncthreads();
    sc[tid] = rcur[tid];
    __syncthreads();
    for (int off = 1; off < BROWS; off <<= 1) {
        int t = (tid >= off) ? sc[tid - off] : 0;
        __syncthreads();
        sc[tid] += t;
        __syncthreads();
    }
    const int excl = (tid == 0) ? 0 : sc[tid - 1];
    rcur[tid] = s + excl;
    if (tid < rows) offs[row0 + tid] = s + excl;
    if (bk == nbuk - 1 && tid == 0) offs[N] = e;
    __syncthreads();
    for (int i = s + tid; i < e; i += 512) {
        const u32 cv = tcv[i];
        const int lr = trow[i];
        const int p = atomicAdd(&rcur[lr], 1);
        scv[p] = cv;
    }
}

// ---------------------------------------------------------------------------
// Fallback tier kernels (per-row global cursors / atomic scatter)
// ---------------------------------------------------------------------------
__global__ void hist_k(const int* __restrict__ erow, int* __restrict__ cnt, int E) {
    const int e4 = (blockIdx.x * blockDim.x + threadIdx.x) * 4;
    if (e4 + 3 < E) {
        const int4 r = *reinterpret_cast<const int4*>(erow + e4);
        atomicAdd(&cnt[r.x], 1);
        atomicAdd(&cnt[r.y], 1);
        atomicAdd(&cnt[r.z], 1);
        atomicAdd(&cnt[r.w], 1);
    } else {
        for (int e = e4; e < E; ++e) atomicAdd(&cnt[erow[e]], 1);
    }
}

__global__ void scanA_k(const int* __restrict__ cnt, int* __restrict__ offs,
                        int* __restrict__ bsums, int N) {
    __shared__ int sh[SCAN_T];
    const int base = blockIdx.x * SCAN_CHUNK + threadIdx.x * SCAN_E;
    int v[SCAN_E];
    int s = 0;
#pragma unroll
    for (int j = 0; j < SCAN_E; ++j) {
        int idx = base + j;
        int c = (idx < N) ? cnt[idx] : 0;
        v[j] = s;
        s += c;
    }
    sh[threadIdx.x] = s;
    __syncthreads();
    for (int off = 1; off < SCAN_T; off <<= 1) {
        int t = (threadIdx.x >= off) ? sh[threadIdx.x - off] : 0;
        __syncthreads();
        sh[threadIdx.x] += t;
        __syncthreads();
    }
    const int excl = (threadIdx.x == 0) ? 0 : sh[threadIdx.x - 1];
    if (threadIdx.x == SCAN_T - 1) bsums[blockIdx.x] = sh[SCAN_T - 1];
#pragma unroll
    for (int j = 0; j < SCAN_E; ++j) {
        int idx = base + j;
        if (idx < N) offs[idx] = v[j] + excl;
    }
}

__global__ void scanB_k(int* __restrict__ bsums, int nb) {
    __shared__ int sh[1024];
    const int tid = threadIdx.x;
    if (tid < nb) sh[tid] = bsums[tid];
    __syncthreads();
    if (tid == 0) {
        int s = 0;
        for (int i = 0; i < nb; ++i) { int t = sh[i]; sh[i] = s; s += t; }
    }
    __syncthreads();
    if (tid < nb) bsums[tid] = sh[tid];
}

__global__ void scanC_k(int* __restrict__ offs, int* __restrict__ cursor,
                        const int* __restrict__ bsums, int N, int E) {
    const int i = blockIdx.x * blockDim.x + threadIdx.x;
    if (i < N) {
        int v = offs[i] + bsums[i / SCAN_CHUNK];
        offs[i] = v;
        cursor[i] = v;
    }
    if (i == 0) offs[N] = E;
}

__global__ void reorder_k(const int* __restrict__ erow, const int* __restrict__ ecol,
                          const float* __restrict__ ev, int* __restrict__ cursor,
                          u32* __restrict__ scv, int E) {
    const int e4 = (blockIdx.x * blockDim.x + threadIdx.x) * 4;
    if (e4 + 3 < E) {
        const int4   r = *reinterpret_cast<const int4*>(erow + e4);
        const int4   c = *reinterpret_cast<const int4*>(ecol + e4);
        const float4 v = *reinterpret_cast<const float4*>(ev + e4);
        int p;
        p = atomicAdd(&cursor[r.x], 1); scv[p] = packCV(c.x, v.x);
        p = atomicAdd(&cursor[r.y], 1); scv[p] = packCV(c.y, v.y);
        p = atomicAdd(&cursor[r.z], 1); scv[p] = packCV(c.z, v.z);
        p = atomicAdd(&cursor[r.w], 1); scv[p] = packCV(c.w, v.w);
    } else {
        for (int e = e4; e < E; ++e) {
            int p = atomicAdd(&cursor[erow[e]], 1);
            scv[p] = packCV(ecol[e], ev[e]);
        }
    }
}

// ---------------------------------------------------------------------------
// Fused segment-sum + bi-interaction MLP — EXACT R9/R11 body (measured 214us,
// best of 6 measured variants). Perturbation ledger: VMEM hints -42%,
// pair-packing -15%, weight pinning neutral, DS-reduction -21%, occupancy
// forcing (waves=8 -> VGPR 32, scratch spill, FETCH 209MB->2.6GB) -336%.
// This body is the measured local optimum; VGPR=84, 6 waves/SIMD is the
// right operating point.
// ---------------------------------------------------------------------------
__device__ __forceinline__ float lrelu(float x) {
    return fmaxf(x, 0.f) + 0.01f * fminf(x, 0.f);
}

template <bool BF16>
__global__ __launch_bounds__(256, 2) void fused_k(const float* __restrict__ ego,
                                                  const u16* __restrict__ egoh,
                                                  const float* __restrict__ W1,
                                                  const float* __restrict__ b1,
                                                  const float* __restrict__ W2,
                                                  const float* __restrict__ b2,
                                                  const int* __restrict__ offs,
                                                  const u32* __restrict__ scv,
                                                  float* __restrict__ out,
                                                  int N, int rowsPerWave) {
    __shared__ __align__(16) float xsh[4][2][DIM];
    const int lane = threadIdx.x & 63;
    const int wid  = threadIdx.x >> 6;

    float w1[DIM], w2[DIM];
#pragma unroll
    for (int k = 0; k < DIM; ++k) {
        w1[k] = W1[k * DIM + lane];
        w2[k] = W2[k * DIM + lane];
    }
    const float bb1 = b1[lane];
    const float bb2 = b2[lane];

    const int waveId = blockIdx.x * 4 + wid;
    const int r0 = waveId * rowsPerWave;
    const int r1 = min(N, r0 + rowsPerWave);

    for (int row = r0; row < r1; ++row) {
        const int s = offs[row];
        const int t = offs[row + 1];
        float acc = 0.f;
        for (int base = s; base < t; base += 64) {
            const int m = min(64, t - base);
            const u32 cv = (lane < m) ? scv[base + lane] : 0u;
            for (int j = 0; j < m; j += 8) {
                u32 uu[8];
#pragma unroll
                for (int i = 0; i < 8; ++i) {
                    const int sj = j + i;
                    const u32 x = (u32)__shfl((int)cv, sj & 63);
                    uu[i] = (sj < m) ? x : 0u;
                }
                float g[8];
#pragma unroll
                for (int i = 0; i < 8; ++i) {
                    if (BF16) g[i] = bf2f(egoh[(uu[i] >> 14) * DIM + lane]);
                    else      g[i] = ego[(uu[i] >> 14) * DIM + lane];
                }
                const float sc = 1.f / 16384.f;
#pragma unroll
                for (int i = 0; i < 8; ++i)
                    acc = fmaf((float)(uu[i] & 16383u) * sc, g[i], acc);
            }
        }
        // ---- fused bi-interaction MLP (x broadcast via LDS) ----
        const int obase = row * DIM + lane;
        const float e = ego[obase];
        xsh[wid][0][lane] = e + acc;
        xsh[wid][1][lane] = e * acc;
        float a1 = bb1, a2 = bb2;
#pragma unroll
        for (int k4 = 0; k4 < 16; ++k4) {
            const float4 xa = *reinterpret_cast<const float4*>(&xsh[wid][0][k4 * 4]);
            const float4 xm = *reinterpret_cast<const float4*>(&xsh[wid][1][k4 * 4]);
            a1 = fmaf(xa.x, w1[4 * k4 + 0], a1);
            a1 = fmaf(xa.y, w1[4 * k4 + 1], a1);
            a1 = fmaf(xa.z, w1[4 * k4 + 2], a1);
            a1 = fmaf(xa.w, w1[4 * k4 + 3], a1);
            a2 = fmaf(xm.x, w2[4 * k4 + 0], a2);
            a2 = fmaf(xm.y, w2[4 * k4 + 1], a2);
            a2 = fmaf(xm.z, w2[4 * k4 + 2], a2);
            a2 = fmaf(xm.w, w2[4 * k4 + 3], a2);
        }
        out[obase] = lrelu(a1) + lrelu(a2);
    }
}

// ---------------------------------------------------------------------------
// Atomic fallback path
// ---------------------------------------------------------------------------
__device__ __forceinline__ void atomAddF(float* p, float v) {
    __hip_atomic_fetch_add(p, v, __ATOMIC_RELAXED, __HIP_MEMORY_SCOPE_AGENT);
}

__global__ void scatter_k(const float* __restrict__ ego,
                          const int* __restrict__ erow,
                          const int* __restrict__ ecol,
                          const float* __restrict__ eval_,
                          float* __restrict__ side,
                          long long total16) {
    long long tid = (long long)blockIdx.x * blockDim.x + threadIdx.x;
    if (tid >= total16) return;
    const int e = (int)(tid >> 4);
    const int q = (int)(tid & 15);
    const float4 g = *reinterpret_cast<const float4*>(ego + (size_t)ecol[e] * DIM + q * 4);
    const float v = eval_[e];
    float* dst = side + (size_t)erow[e] * DIM + q * 4;
    atomAddF(dst + 0, g.x * v);
    atomAddF(dst + 1, g.y * v);
    atomAddF(dst + 2, g.z * v);
    atomAddF(dst + 3, g.w * v);
}

__global__ __launch_bounds__(256) void mlp_k(const float* __restrict__ ego,
                                             const float* __restrict__ W1,
                                             const float* __restrict__ b1,
                                             const float* __restrict__ W2,
                                             const float* __restrict__ b2,
                                             float* out, int nNodes) {
    __shared__ __align__(16) float xsh[4][2][DIM];
    const int lane = threadIdx.x & 63;
    const int wid  = threadIdx.x >> 6;
    float w1[DIM], w2[DIM];
#pragma unroll
    for (int k = 0; k < DIM; ++k) {
        w1[k] = W1[k * DIM + lane];
        w2[k] = W2[k * DIM + lane];
    }
    const float bb1 = b1[lane];
    const float bb2 = b2[lane];
    const int waveId = blockIdx.x * 4 + wid;
    const int nWaves = gridDim.x * 4;
    for (int n = waveId; n < nNodes; n += nWaves) {
        const size_t base = (size_t)n * DIM + lane;
        const float e = ego[base];
        const float s = out[base];
        xsh[wid][0][lane] = e + s;
        xsh[wid][1][lane] = e * s;
        float acc1 = bb1, acc2 = bb2;
#pragma unroll
        for (int k4 = 0; k4 < 16; ++k4) {
            const float4 a = *reinterpret_cast<const float4*>(&xsh[wid][0][k4 * 4]);
            const float4 m = *reinterpret_cast<const float4*>(&xsh[wid][1][k4 * 4]);
            acc1 = fmaf(a.x, w1[4 * k4 + 0], acc1);
            acc1 = fmaf(a.y, w1[4 * k4 + 1], acc1);
            acc1 = fmaf(a.z, w1[4 * k4 + 2], acc1);
            acc1 = fmaf(a.w, w1[4 * k4 + 3], acc1);
            acc2 = fmaf(m.x, w2[4 * k4 + 0], acc2);
            acc2 = fmaf(m.y, w2[4 * k4 + 1], acc2);
            acc2 = fmaf(m.z, w2[4 * k4 + 2], acc2);
            acc2 = fmaf(m.w, w2[4 * k4 + 3], acc2);
        }
        const float r1 = fmaxf(acc1, 0.f) + 0.01f * fminf(acc1, 0.f);
        const float r2 = fmaxf(acc2, 0.f) + 0.01f * fminf(acc2, 0.f);
        out[base] = r1 + r2;
    }
}

// ---------------------------------------------------------------------------
extern "C" void kernel_launch(void* const* d_in, const int* in_sizes, int n_in,
                              void* d_out, int out_size, void* d_ws, size_t ws_size,
                              hipStream_t stream) {
    const float* ego  = (const float*)d_in[0];
    const float* W1   = (const float*)d_in[1];
    const float* b1   = (const float*)d_in[2];
    const float* W2   = (const float*)d_in[3];
    const float* b2   = (const float*)d_in[4];
    const int*   erow = (const int*)d_in[5];
    const int*   ecol = (const int*)d_in[6];
    const float* ev   = (const float*)d_in[7];
    float* out = (float*)d_out;

    const int N = in_sizes[0] / DIM;
    const int E = in_sizes[5];

    auto align256 = [](size_t x) { return (x + 63) & ~(size_t)63; };  // int units
    const int nbuk = (N + BROWS - 1) >> BSHIFT;

    size_t o_cnt     = 0;                                    // N (fallback)
    size_t o_offs    = align256(o_cnt + N);                  // N+1
    size_t o_cursor  = align256(o_offs + N + 1);             // N (fallback)
    size_t o_bsums   = align256(o_cursor + N);               // 1024 (fallback)
    size_t o_scv     = align256(o_bsums + 1024);             // E
    size_t o_egoh    = align256(o_scv + E);                  // N*DIM u16 = N*32 ints
    size_t o_bhist   = align256(o_egoh + (size_t)N * (DIM / 2));
    size_t o_bktTot  = align256(o_bhist + (size_t)MAXBUK * PBLK);
    size_t o_bktBase = align256(o_bktTot + MAXBUK);
    size_t o_tcv     = align256(o_bktBase + MAXBUK + 1);
    size_t o_trow    = align256(o_tcv + E);
    size_t need_main = (o_trow + (size_t)(E + 1) / 2) * sizeof(int);
    size_t need_fb1  = (o_bhist) * sizeof(int);              // through egoh
    size_t need_fb2  = (o_egoh) * sizeof(int);               // through scv

    const bool packOK = (N <= (1 << 18));

    if (!packOK || ws_size < need_fb2) {
        hipMemsetAsync(out, 0, (size_t)out_size * sizeof(float), stream);
        const long long total16 = (long long)E * 16;
        scatter_k<<<(int)((total16 + 255) / 256), 256, 0, stream>>>(ego, erow, ecol, ev, out, total16);
        mlp_k<<<1024, 256, 0, stream>>>(ego, W1, b1, W2, b2, out, N);
        return;
    }

    int* ws = (int*)d_ws;
    int* cnt     = ws + o_cnt;
    int* offs    = ws + o_offs;
    int* cursor  = ws + o_cursor;
    int* bsums   = ws + o_bsums;
    u32* scv     = (u32*)(ws + o_scv);
    u16* egoh    = (u16*)(ws + o_egoh);
    int* bhist   = ws + o_bhist;
    int* bktTot  = ws + o_bktTot;
    int* bktBase = ws + o_bktBase;
    u32* tcv     = (u32*)(ws + o_tcv);
    u16* trow    = (u16*)(ws + o_trow);

    const bool useBF16  = ws_size >= need_fb1;
    const bool useRadix = (ws_size >= need_main) && (nbuk <= MAXBUK) && useBF16;

    if (useRadix) {
        const int CH = (((E + PBLK - 1) / PBLK) + 3) & ~3;
        histb_k<<<PBLK, 256, 0, stream>>>(erow, bhist, E, CH, nbuk);
        bbase_k<<<nbuk, SCAN_T, 0, stream>>>(bhist, bktTot);
        scanBk_k<<<1, 512, 0, stream>>>(bktTot, bktBase, nbuk);
        part_k<<<PBLK, 256, 0, stream>>>(erow, ecol, ev, bhist, bktBase, tcv, trow, E, CH, nbuk);
        final2_k<<<nbuk, 512, 0, stream>>>(tcv, trow, bktBase, offs, scv, N, nbuk);
        const int n4 = N * DIM / 4;
        cvt_k<<<(n4 + 255) / 256, 256, 0, stream>>>(ego, egoh, n4);
    } else {
        const int nb = (N + SCAN_CHUNK - 1) / SCAN_CHUNK;
        hipMemsetAsync(cnt, 0, (size_t)N * sizeof(int), stream);
        hist_k<<<(E / 4 + 255) / 256, 256, 0, stream>>>(erow, cnt, E);
        if (useBF16) {
            const int n4 = N * DIM / 4;
            cvt_k<<<(n4 + 255) / 256, 256, 0, stream>>>(ego, egoh, n4);
        }
        scanA_k<<<nb, SCAN_T, 0, stream>>>(cnt, offs, bsums, N);
        scanB_k<<<1, 1024, 0, stream>>>(bsums, nb);
        scanC_k<<<(N + 255) / 256, 256, 0, stream>>>(offs, cursor, bsums, N, E);
        reorder_k<<<(E / 4 + 255) / 256, 256, 0, stream>>>(erow, ecol, ev, cursor, scv, E);
    }

    const int nBlocks = 2048;
    const int nWaves = nBlocks * 4;
    const int rowsPerWave = (N + nWaves - 1) / nWaves;
    if (useBF16) {
        fused_k<true><<<nBlocks, 256, 0, stream>>>(ego, egoh, W1, b1, W2, b2, offs, scv, out, N, rowsPerWave);
    } else {
        fused_k<false><<<nBlocks, 256, 0, stream>>>(ego, egoh, W1, b1, W2, b2, offs, scv, out, N, rowsPerWave);
    }
}